// Round 3
// baseline (248.571 us; speedup 1.0000x reference)
//
#include <hip/hip_runtime.h>
#include <math.h>

// DivMergedLayer1: reference collapses to out = x except 4 floats per row.
//   N=32, D=128, F=4096, B=8192. Flat row layout: x[b, n, d] -> xr[n*128 + d].
//   op  = xr[67]            (OP_START+OPCODE = 64+3, nibble row 0)
//   r60 = relu(60*op); inv60 = fp32(1/60)
//   P   = sum_{i=0..31} 2^i * xr[i*128 + 0]     (gate reads NIB_A = col 0)
//   delta_c[s] = -(r60 * xr[s]) * inv60    for s in {2,3,4,5}
//   delta_g[2] =  r60 * P * inv60
//   float64 path over d_i = (double)xr[i*128 + 1]   (NIB_B = col 1):
//     score_i = d_i > 0.5 ? log(max(d_i*2^i, 0.5)) : -60
//     mx = max_i score_i; sum_ex = sum_i exp(score_i - mx)
//     recip = exp(-mx)/max(sum_ex, 1e-30)
//   out[2] = x2 - r60*x2/60 + r60*P/60
//   out[3,4] = x - r60*x/60
//   out[5] = x5 - r60*x5/60 + op*(float)recip
//   out elsewhere = x exactly.
//
// R2 showed the barrier-coupled design latency-bound at 2.56 TB/s (fillBuffer
// hits 6.4 TB/s in the same capture). This version decouples: fix blocks
// (one wave per row, no barrier) own the first 32 B of each out row; copy
// blocks are a pure barrier-free stream of the remaining 16 KiB - 32 B.

#define DDIM 128
#define FDIM 4096

__global__ __launch_bounds__(256) void div_merged_kernel(
    const float* __restrict__ x, float* __restrict__ out, int rows) {
  const int bid = blockIdx.x;
  const int t = threadIdx.x;
  const int nfix = rows >> 2;  // 4 rows (waves) per fix block

  if (bid < nfix) {
    // ---- fix path: wave w handles row bid*4 + w; writes out flats 0..7 ----
    const int wave = t >> 6;
    const int lane = t & 63;
    const long long row = (long long)bid * 4 + wave;
    const float* __restrict__ xr = x + row * (long long)FDIM;
    float* __restrict__ orow = out + row * (long long)FDIM;

    const bool active = lane < 32;
    double score = -60.0;
    double p = 0.0;
    if (active) {
      const float2 ab = *(const float2*)(xr + lane * DDIM);  // cols 0,1
      const double pw = (double)(1ULL << lane);               // 2^lane exact
      p = (double)ab.x * pw;
      const double d = (double)ab.y;
      score = (d > 0.5) ? log(fmax(d * pw, 0.5)) : -60.0;
    }
    // 64-lane butterfly max; inactive lanes hold -60 (matches ref when all
    // real scores are -60, and is dominated otherwise).
    double mx = score;
#pragma unroll
    for (int off = 1; off < 64; off <<= 1)
      mx = fmax(mx, __shfl_xor(mx, off));
    double ex = active ? exp(score - mx) : 0.0;
#pragma unroll
    for (int off = 1; off < 64; off <<= 1) {
      ex += __shfl_xor(ex, off);
      p  += __shfl_xor(p, off);
    }
    if (lane == 0) {
      const float op    = xr[67];
      const float r60   = fmaxf(60.0f * op, 0.0f);
      const float inv60 = (float)(1.0 / 60.0);
      const double recip = exp(-mx) / fmax(ex, 1e-30);
      const float Pf = (float)p;
      float4 lo = *(const float4*)xr;        // flats 0..3
      float4 hi = *(const float4*)(xr + 4);  // flats 4..7
      const float dc2 = -((r60 * lo.z) * inv60);
      const float dc3 = -((r60 * lo.w) * inv60);
      const float dc4 = -((r60 * hi.x) * inv60);
      const float dc5 = -((r60 * hi.y) * inv60);
      const float dg2 = (r60 * Pf) * inv60;
      lo.z = lo.z + (dc2 + dg2);
      lo.w = lo.w + dc3;
      hi.x = hi.x + dc4;
      hi.y = (hi.y + dc5) + op * (float)recip;
      *(float4*)orow = lo;
      *(float4*)(orow + 4) = hi;
    }
  } else {
    // ---- copy path: pure stream of one row, skipping first 2 float4 ----
    const long long row = bid - nfix;
    const float4* __restrict__ x4 = (const float4*)(x + row * (long long)FDIM);
    float4* __restrict__ o4 = (float4*)(out + row * (long long)FDIM);
#pragma unroll
    for (int k = 0; k < 4; ++k) {
      const int idx = k * 256 + t;  // 0..1023 float4 per row
      if (idx >= 2) o4[idx] = x4[idx];
    }
  }
}

extern "C" void kernel_launch(void* const* d_in, const int* in_sizes, int n_in,
                              void* d_out, int out_size, void* d_ws, size_t ws_size,
                              hipStream_t stream) {
  const float* x = (const float*)d_in[0];  // (B, 32, 128) fp32
  float* out = (float*)d_out;              // (B, 32, 128) fp32
  const int rows = in_sizes[0] / FDIM;     // B = 8192
  const int nfix = rows >> 2;
  div_merged_kernel<<<rows + nfix, 256, 0, stream>>>(x, out, rows);
}